// Round 16
// baseline (216.123 us; speedup 1.0000x reference)
//
#include <hip/hip_runtime.h>

#define ALPHA 0.9f
#define EPS 1e-6f
#define LOG2A  (-0.15200309344504995f)   // log2(0.9)
#define A64F   (1.1790184577738583e-3f)  // 0.9^64

constexpr int T_DIM  = 4096;
constexpr int B_DIM  = 16;
constexpr int D_DIM  = 1024;
constexpr int N_DIM  = 64;
constexpr int NPROJ  = 192;
constexpr int NCHUNK = 64;

typedef float  f32x4   __attribute__((ext_vector_type(4)));
typedef _Float16 f16x8 __attribute__((ext_vector_type(8)));

__device__ __forceinline__ float powA(float e) {   // ALPHA^e
  return exp2f(e * LOG2A);
}
__device__ __forceinline__ float rdlane(float v, int src) {
  return __builtin_bit_cast(float,
      __builtin_amdgcn_readlane(__builtin_bit_cast(int, v), src));
}

__device__ __constant__ float APOW[16] = {
  1.f, 0.9f, 0.81f, 0.729f, 0.6561f, 0.59049f, 0.531441f, 0.4782969f,
  0.43046721f, 0.387420489f, 0.3486784401f, 0.31381059609f,
  0.282429536481f, 0.2541865828329f, 0.22876792454961f, 0.205891132094649f};
__device__ __constant__ float AINV[16] = {
  1.f, 1.1111111111f, 1.2345679012f, 1.3717421125f, 1.5241579028f,
  1.6935087809f, 1.8816764232f, 2.0907515814f, 2.3230573126f,
  2.5811747918f, 2.8679719909f, 3.1866355454f, 3.5407061616f,
  3.9341179573f, 4.3712421748f, 4.8569357498f};

// ---------------- W pre-conversion: fp32 -> f16, frag-step layout ----------------
__global__ __launch_bounds__(256) void convert_w(
    const float* __restrict__ W, _Float16* __restrict__ w16)
{
  int i = blockIdx.x * 256 + threadIdx.x;
  int c = i >> 10, k = i & 1023;
  w16[(k >> 5) * (NPROJ * 32) + c * 32 + (k & 31)] = (_Float16)W[i];
}

// ---------------- MFMA projection GEMM: pure f16, fused k-normalize ----------------
constexpr int BM = 128, BK = 32, NS = D_DIM / BK;

__global__ __launch_bounds__(512, 2) void proj_gemm(
    const float* __restrict__ x, const _Float16* __restrict__ w16,
    _Float16* __restrict__ pf16)
{
  __shared__ __align__(16) _Float16 smem[2 * BM * BK + 2 * NPROJ * BK]; // 40 KB
  __shared__ float nrm[BM][2];

  _Float16 (*As)[BM * BK]    = (_Float16(*)[BM * BK])smem;
  _Float16 (*Bs)[NPROJ * BK] = (_Float16(*)[NPROJ * BK])(smem + 2 * BM * BK);
  _Float16 (*ep)[200]        = (_Float16(*)[200])smem;   // 64 x 200 f16 = 25.6 KB

  const int tid  = threadIdx.x;
  const int w    = tid >> 6, lane = tid & 63;
  const int wr   = w >> 2, wc = w & 3;      // wave grid 2x4
  const int fr   = lane & 15, fg = lane >> 4;
  const int row0 = blockIdx.x * BM;

  const int arow = tid >> 2, akq = (tid & 3) * 8;
  const float* aSrc = x + (size_t)(row0 + arow) * D_DIM + akq;

  f32x4 acc[4][3];
#pragma unroll
  for (int i = 0; i < 4; ++i)
#pragma unroll
    for (int j = 0; j < 3; ++j) acc[i][j] = (f32x4){0.f, 0.f, 0.f, 0.f};

  float4 a0, a1;

  auto loadA = [&](int s) {
    const float* p = aSrc + s * BK;
    a0 = *(const float4*)p;
    a1 = *(const float4*)(p + 4);
  };
  auto writeA = [&](int buf) {
    f16x8 h;
    h[0] = (_Float16)a0.x; h[1] = (_Float16)a0.y;
    h[2] = (_Float16)a0.z; h[3] = (_Float16)a0.w;
    h[4] = (_Float16)a1.x; h[5] = (_Float16)a1.y;
    h[6] = (_Float16)a1.z; h[7] = (_Float16)a1.w;
    *(f16x8*)&As[buf][arow * BK + akq] = h;
  };
  auto stageB = [&](int buf, int s) {
#pragma unroll
    for (int j = 0; j < 2; ++j) {
      const int sl = j * 8 + w;
      if (sl < 12) {
        const _Float16* src = w16 + (size_t)s * (NPROJ * 32) + sl * 512;
        __builtin_amdgcn_global_load_lds(
            (const __attribute__((address_space(1))) unsigned int*)(src) + lane * 4,
            (__attribute__((address_space(3))) unsigned int*)&Bs[buf][sl * 512],
            16, 0, 0);
      }
    }
  };
  auto compute = [&](int buf) {
    f16x8 af[4];
#pragma unroll
    for (int ar = 0; ar < 4; ++ar)
      af[ar] = *(const f16x8*)&As[buf][(wr * 64 + ar * 16 + fr) * BK + fg * 8];
#pragma unroll
    for (int bc = 0; bc < 3; ++bc) {
      f16x8 bf = *(const f16x8*)&Bs[buf][(wc * 48 + bc * 16 + fr) * BK + fg * 8];
#pragma unroll
      for (int ar = 0; ar < 4; ++ar)
        acc[ar][bc] = __builtin_amdgcn_mfma_f32_16x16x32_f16(af[ar], bf, acc[ar][bc], 0, 0, 0);
    }
  };

  loadA(0);
  stageB(0, 0);
  writeA(0);
  __syncthreads();

  int buf = 0;
  for (int s = 0; s < NS; ++s) {
    if (s + 1 < NS) {
      loadA(s + 1);
      stageB(buf ^ 1, s + 1);
    }
    compute(buf);
    if (s + 1 < NS) writeA(buf ^ 1);
    __syncthreads();
    buf ^= 1;
  }

  // ---- fused k-normalization (cols 0..63 are k) ----
  if (wc < 2) {
#pragma unroll
    for (int ar = 0; ar < 4; ++ar)
#pragma unroll
      for (int r = 0; r < 4; ++r) {
        float ss;
        if (wc == 0) {
          const float p0 = acc[ar][0][r], p1 = acc[ar][1][r], p2 = acc[ar][2][r];
          ss = p0 * p0 + p1 * p1 + p2 * p2;    // cols 0..47
        } else {
          const float p0 = acc[ar][0][r];
          ss = p0 * p0;                         // cols 48..63
        }
        ss += __shfl_xor(ss, 1, 64);
        ss += __shfl_xor(ss, 2, 64);
        ss += __shfl_xor(ss, 4, 64);
        ss += __shfl_xor(ss, 8, 64);
        if (fr == 0) nrm[wr * 64 + ar * 16 + fg * 4 + r][wc] = ss;
      }
  }
  __syncthreads();
  if (wc < 2) {
#pragma unroll
    for (int ar = 0; ar < 4; ++ar)
#pragma unroll
      for (int r = 0; r < 4; ++r) {
        const int row = wr * 64 + ar * 16 + fg * 4 + r;
        const float rn = 1.0f / (sqrtf(nrm[row][0] + nrm[row][1]) + EPS);
        if (wc == 0) {
          acc[ar][0][r] *= rn; acc[ar][1][r] *= rn; acc[ar][2][r] *= rn;
        } else {
          acc[ar][0][r] *= rn;
        }
      }
  }

  // ---- epilogue: LDS transpose -> coalesced f16x8 stores, two 64-row passes ----
#pragma unroll
  for (int p = 0; p < 2; ++p) {
    __syncthreads();
    if (wr == p) {
#pragma unroll
      for (int ar = 0; ar < 4; ++ar)
#pragma unroll
        for (int bc = 0; bc < 3; ++bc)
#pragma unroll
          for (int r = 0; r < 4; ++r)
            ep[ar * 16 + fg * 4 + r][wc * 48 + bc * 16 + fr] = (_Float16)acc[ar][bc][r];
    }
    __syncthreads();
#pragma unroll
    for (int u = 0; u < 3; ++u) {
      const int g = u * 512 + tid;        // f16x8 index in [0, 1536)
      const int rr = g / 24, cc = g - rr * 24;
      *(f16x8*)(pf16 + (size_t)(row0 + p * 64 + rr) * NPROJ + cc * 8) =
          *(const f16x8*)&ep[rr][cc * 8];
    }
  }
}

// ---------------- chunked scan (SW formulation), 1 wave, 37.1 KB LDS ----------------
__global__ __launch_bounds__(64) void scan_sw(
    const _Float16* __restrict__ pf16, const float* __restrict__ S0,
    float* __restrict__ out, float* __restrict__ Sfin)
{
  __shared__ __align__(16) _Float16 sK[64][72];     // 9216
  __shared__ __align__(16) _Float16 sQ[32][72];     // 4608 (Q half)
  __shared__ __align__(16) _Float16 sSW[64][72];    // 9216
  __shared__ __align__(16) _Float16 sDT[64][72];    // 9216 delta^T [i][tau]
  __shared__ __align__(16) _Float16 sBB[16][72];    // 2304 bridge+combine [t][i]
  __shared__ __align__(16) _Float16 uGt[2][16][40]; // 2560 gram tiles (dbuf)

  const int lane = threadIdx.x;
  const int fr = lane & 15, fg = lane >> 4;
  const int b = blockIdx.x & (B_DIM - 1), c = blockIdx.x >> 4;
  const int t0o = c * 64;
  const bool c0 = (c == 0);

  // zero sDT (bridge/H MFMAs read not-yet-written / padded columns: 0*NaN = NaN)
#pragma unroll
  for (int u = 0; u < 36; ++u) ((unsigned*)&sDT[0][0])[u * 64 + lane] = 0u;
  // zero uGt entirely (mm reads cols 16..31 expect 0)
#pragma unroll
  for (int u = 0; u < 10; ++u) ((unsigned*)&uGt[0][0][0])[u * 64 + lane] = 0u;

  auto stage64 = [&](_Float16 (*dst)[72], int t0, int sel) {
#pragma unroll
    for (int it = 0; it < 8; ++it) {
      int g = it * 64 + lane, t = g >> 3, c8 = g & 7;
      uint4 v = *(const uint4*)(pf16 + ((size_t)(t0 + t) * B_DIM + b) * NPROJ + sel + c8 * 8);
      *(uint4*)&dst[t][c8 * 8] = v;
    }
  };
  auto stageQ = [&](int half) {
#pragma unroll
    for (int it = 0; it < 4; ++it) {
      int g = it * 64 + lane, t = g >> 3, c8 = g & 7;
      uint4 v = *(const uint4*)(pf16 +
          ((size_t)(t0o + half * 32 + t) * B_DIM + b) * NPROJ + 128 + c8 * 8);
      *(uint4*)&sQ[t][c8 * 8] = v;
    }
  };

  auto dotT = [&](const _Float16* A, int sa, int ra, const _Float16* B, int sb, int rb) {
    f32x4 a = (f32x4){0.f, 0.f, 0.f, 0.f};
    f16x8 af = *(const f16x8*)(A + (ra + fr) * sa + fg * 8);
    f16x8 bf = *(const f16x8*)(B + (rb + fr) * sb + fg * 8);
    a = __builtin_amdgcn_mfma_f32_16x16x32_f16(af, bf, a, 0, 0, 0);
    af = *(const f16x8*)(A + (ra + fr) * sa + 32 + fg * 8);
    bf = *(const f16x8*)(B + (rb + fr) * sb + 32 + fg * 8);
    a = __builtin_amdgcn_mfma_f32_16x16x32_f16(af, bf, a, 0, 0, 0);
    return a;
  };

  // in-place K transpose: single wave; compiler barrier pins read-all-then-write order
  auto transposeK = [&]() {
    f16x8 rv[8];
#pragma unroll
    for (int q8 = 0; q8 < 8; ++q8) rv[q8] = *(const f16x8*)&sK[lane][q8 * 8];
    asm volatile("" ::: "memory");
#pragma unroll
    for (int q8 = 0; q8 < 8; ++q8)
#pragma unroll
      for (int e = 0; e < 8; ++e) sK[q8 * 8 + e][lane] = rv[q8][e];
  };

  // forward-substitution solve; diag Grams pre-hoisted to regs; combine folded into bacc
  auto solve = [&](bool isW, int t0v) {
    // all 4 diagonal grams up front (independent -> pipelined)
    f32x4 gdA[4];
#pragma unroll
    for (int k = 0; k < 4; ++k)
      gdA[k] = dotT(&sK[0][0], 72, k * 16, &sK[0][0], 72, k * 16);

#pragma unroll
    for (int k = 0; k < 4; ++k) {
      // v prefetch (latency hides under grams below)
      _Float16 vr[16];
#pragma unroll
      for (int t = 0; t < 16; ++t)
        vr[t] = pf16[((size_t)(t0v + k * 16 + t) * B_DIM + b) * NPROJ + 64 + lane];

      f32x4 bacc[4];
#pragma unroll
      for (int ib = 0; ib < 4; ++ib) bacc[ib] = (f32x4){0.f, 0.f, 0.f, 0.f};

      // bridge (cross-block) part, double-buffered gram tiles
      if (k > 0) {
        for (int j = 0; j < k; ++j) {
          f32x4 g = dotT(&sK[0][0], 72, k * 16, &sK[0][0], 72, j * 16);
#pragma unroll
          for (int r = 0; r < 4; ++r) {
            const int tl = fg * 4 + r;
            const float e = isW ? (float)(16 * k + tl - 64)
                                : (float)(16 * (k - j) + tl - fr - 1);
            uGt[j & 1][tl][fr] = (_Float16)(g[r] * powA(e));
          }
#pragma unroll
          for (int ib = 0; ib < 4; ++ib) {
            f16x8 af = *(const f16x8*)&uGt[j & 1][fr][fg * 8];
            f16x8 bf = *(const f16x8*)&sDT[ib * 16 + fr][j * 16 + fg * 8];
            bacc[ib] = __builtin_amdgcn_mfma_f32_16x16x32_f16(af, bf, bacc[ib], 0, 0, 0);
          }
        }
      }

      // combine: bacc[tj] += a^{16k+t} * (SW.kn)[t][i]   (O-solve only; same C-layout)
      if (!isW) {
#pragma unroll
        for (int tj = 0; tj < 4; ++tj) {
          f32x4 a = dotT(&sK[0][0], 72, k * 16, &sSW[0][0], 72, tj * 16);
#pragma unroll
          for (int r = 0; r < 4; ++r)
            bacc[tj][r] = fmaf(a[r], powA((float)(16 * k + fg * 4 + r)), bacc[tj][r]);
        }
      }

      const bool useBB = (!isW || k > 0);
      if (useBB) {
#pragma unroll
        for (int ib = 0; ib < 4; ++ib)
#pragma unroll
          for (int r = 0; r < 4; ++r)
            sBB[fg * 4 + r][ib * 16 + fr] = (_Float16)bacc[ib][r];
      }

      const f32x4 gd = gdA[k];

      // serial 16 steps (tree'd partials)
      float d[16], dA[16];
#pragma unroll
      for (int t = 0; t < 16; ++t) {
        float base = (float)vr[t];
        if (useBB) base -= (float)sBB[t][lane];
        float p0 = 0.f, p1 = 0.f, p2 = 0.f, p3 = 0.f;
#pragma unroll
        for (int tau = 0; tau < t; ++tau) {
          const float gv = rdlane(gd[t & 3], (t >> 2) * 16 + tau);
          if ((tau & 3) == 0)      p0 = fmaf(gv, dA[tau], p0);
          else if ((tau & 3) == 1) p1 = fmaf(gv, dA[tau], p1);
          else if ((tau & 3) == 2) p2 = fmaf(gv, dA[tau], p2);
          else                     p3 = fmaf(gv, dA[tau], p3);
        }
        const float sum = (p0 + p1) + (p2 + p3);
        d[t] = (t == 0) ? base : fmaf(-APOW[t - 1], sum, base);
        dA[t] = d[t] * AINV[t];
      }
#pragma unroll
      for (int t8 = 0; t8 < 2; ++t8) {
        f16x8 pack;
#pragma unroll
        for (int e = 0; e < 8; ++e) {
          const int tl = t8 * 8 + e;
          const float sc = isW ? powA((float)(63 - (16 * k + tl))) : 1.f;
          pack[e] = (_Float16)(d[tl] * sc);
        }
        *(f16x8*)&sDT[lane][k * 16 + t8 * 8] = pack;
      }
    }
  };

  // ---------------- phase W -> SW ----------------
  if (!c0) {
    stage64(sK, t0o - 64, 0);
    solve(true, t0o - 64);        // sDT = a^{63-tau} * delta_w
    transposeK();                 // sK := Kw^T (in place)
#pragma unroll
    for (int ti = 0; ti < 4; ++ti)
#pragma unroll
      for (int tj = 0; tj < 4; ++tj) {
        f32x4 a = dotT(&sDT[0][0], 72, ti * 16, &sK[0][0], 72, tj * 16);
#pragma unroll
        for (int r = 0; r < 4; ++r)
          sSW[ti * 16 + fg * 4 + r][tj * 16 + fr] = (_Float16)a[r];
      }
  } else {
#pragma unroll
    for (int it = 0; it < 8; ++it) {
      const int row = it * 8 + (lane >> 3), col = (lane & 7) * 8;
      const float* src = S0 + (size_t)b * 4096 + row * 64 + col;
      const float4 v1 = *(const float4*)src;
      const float4 v2 = *(const float4*)(src + 4);
      f16x8 pk;
      pk[0] = (_Float16)v1.x; pk[1] = (_Float16)v1.y;
      pk[2] = (_Float16)v1.z; pk[3] = (_Float16)v1.w;
      pk[4] = (_Float16)v2.x; pk[5] = (_Float16)v2.y;
      pk[6] = (_Float16)v2.z; pk[7] = (_Float16)v2.w;
      *(f16x8*)&sSW[row][col] = pk;
    }
  }

  // ---------------- phase O ----------------
  stage64(sK, t0o, 0);            // Ko
  stageQ(0);                      // Q rows 0..31 (latency hides under solve)
  solve(false, t0o);              // sDT = delta_o

#pragma unroll
  for (int h2 = 0; h2 < 2; ++h2) {
    if (h2) stageQ(1);
#pragma unroll
    for (int tb2 = 0; tb2 < 2; ++tb2) {
      const int tb = h2 * 2 + tb2;
      // warm: a^{t+1} (SW.q_t)[i]
      f32x4 sq[4];
#pragma unroll
      for (int tj = 0; tj < 4; ++tj) {
        f32x4 a = dotT(&sQ[0][0], 72, tb2 * 16, &sSW[0][0], 72, tj * 16);
#pragma unroll
        for (int r = 0; r < 4; ++r)
          a[r] *= powA((float)(tb * 16 + fg * 4 + r + 1));
        sq[tj] = a;
      }
      // in-phase: sq += Htile x DT (double-buffered gram tiles)
      for (int qb = 0; qb <= tb; ++qb) {
        f32x4 h = dotT(&sQ[0][0], 72, tb2 * 16, &sK[0][0], 72, qb * 16);
#pragma unroll
        for (int r = 0; r < 4; ++r) {
          const int tl = fg * 4 + r;
          const int t = tb * 16 + tl, tau = qb * 16 + fr;
          const float val = (tau <= t) ? h[r] * powA((float)(t - tau)) : 0.f;
          uGt[qb & 1][tl][fr] = (_Float16)val;
        }
#pragma unroll
        for (int ib = 0; ib < 4; ++ib) {
          f16x8 af = *(const f16x8*)&uGt[qb & 1][fr][fg * 8];
          f16x8 bf = *(const f16x8*)&sDT[ib * 16 + fr][qb * 16 + fg * 8];
          sq[ib] = __builtin_amdgcn_mfma_f32_16x16x32_f16(af, bf, sq[ib], 0, 0, 0);
        }
      }
      // outputs
#pragma unroll
      for (int tj = 0; tj < 4; ++tj)
#pragma unroll
        for (int r = 0; r < 4; ++r) {
          const int t = tb * 16 + fg * 4 + r, i = tj * 16 + fr;
          const float Sq = sq[tj][r];
          const float sig = 1.0f / (1.0f + __expf(-Sq));
          out[(size_t)(t0o + t) * 1024 + b * 64 + i] = Sq * Sq * sig;
        }
    }
  }

  // ---------------- final state (c == 63) ----------------
  if (c == NCHUNK - 1) {
#pragma unroll
    for (int t8 = 0; t8 < 8; ++t8) {
      f16x8 v = *(const f16x8*)&sDT[lane][t8 * 8];
#pragma unroll
      for (int e = 0; e < 8; ++e)
        v[e] = (_Float16)((float)v[e] * powA((float)(63 - (t8 * 8 + e))));
      *(f16x8*)&sDT[lane][t8 * 8] = v;
    }
    transposeK();   // sK := Ko^T (in place)
#pragma unroll
    for (int ti = 0; ti < 4; ++ti)
#pragma unroll
      for (int tj = 0; tj < 4; ++tj) {
        f32x4 so = dotT(&sDT[0][0], 72, ti * 16, &sK[0][0], 72, tj * 16);
#pragma unroll
        for (int r = 0; r < 4; ++r) {
          const int i = ti * 16 + fg * 4 + r, j = tj * 16 + fr;
          Sfin[((size_t)b * 64 + i) * 64 + j] = A64F * (float)sSW[i][j] + so[r];
        }
      }
  }
}

extern "C" void kernel_launch(void* const* d_in, const int* in_sizes, int n_in,
                              void* d_out, int out_size, void* d_ws, size_t ws_size,
                              hipStream_t stream)
{
  const float* x  = (const float*)d_in[0];
  const float* S0 = (const float*)d_in[1];
  const float* Wk = (const float*)d_in[2];
  float* out  = (float*)d_out;
  float* Sfin = out + (size_t)T_DIM * B_DIM * N_DIM;

  // ws layout: pf16 (25.17 MB) | w16 (384 KB)
  char* wsb = (char*)d_ws;
  _Float16* pf16 = (_Float16*)(wsb);
  _Float16* w16  = (_Float16*)(wsb + 25165824);

  // MEASUREMENT ROUND: duplicate idempotent launches to infer per-kernel split.
  // dur = C + 2G + 3S with C+G+S ~= 106 (R13)  =>  S ~= dur - 209, G ~= 312 - dur.
  convert_w<<<(NPROJ * D_DIM) / 256, 256, 0, stream>>>(Wk, w16);
  proj_gemm<<<(T_DIM * B_DIM) / BM, 512, 0, stream>>>(x, w16, pf16);
  proj_gemm<<<(T_DIM * B_DIM) / BM, 512, 0, stream>>>(x, w16, pf16);
  scan_sw<<<B_DIM * NCHUNK, 64, 0, stream>>>(pf16, S0, out, Sfin);
  scan_sw<<<B_DIM * NCHUNK, 64, 0, stream>>>(pf16, S0, out, Sfin);
  scan_sw<<<B_DIM * NCHUNK, 64, 0, stream>>>(pf16, S0, out, Sfin);
}

// Round 17
// 103.681 us; speedup vs baseline: 2.0845x; 2.0845x over previous
//
#include <hip/hip_runtime.h>

#define ALPHA 0.9f
#define EPS 1e-6f
#define LOG2A  (-0.15200309344504995f)   // log2(0.9)
#define A64F   (1.1790184577738583e-3f)  // 0.9^64

constexpr int T_DIM  = 4096;
constexpr int B_DIM  = 16;
constexpr int D_DIM  = 1024;
constexpr int N_DIM  = 64;
constexpr int NPROJ  = 192;
constexpr int NCHUNK = 64;

typedef float  f32x4   __attribute__((ext_vector_type(4)));
typedef _Float16 f16x8 __attribute__((ext_vector_type(8)));

__device__ __forceinline__ float powA(float e) {   // ALPHA^e
  return exp2f(e * LOG2A);
}
__device__ __forceinline__ float rdlane(float v, int src) {
  return __builtin_bit_cast(float,
      __builtin_amdgcn_readlane(__builtin_bit_cast(int, v), src));
}

__device__ __constant__ float APOW[16] = {
  1.f, 0.9f, 0.81f, 0.729f, 0.6561f, 0.59049f, 0.531441f, 0.4782969f,
  0.43046721f, 0.387420489f, 0.3486784401f, 0.31381059609f,
  0.282429536481f, 0.2541865828329f, 0.22876792454961f, 0.205891132094649f};
__device__ __constant__ float AINV[16] = {
  1.f, 1.1111111111f, 1.2345679012f, 1.3717421125f, 1.5241579028f,
  1.6935087809f, 1.8816764232f, 2.0907515814f, 2.3230573126f,
  2.5811747918f, 2.8679719909f, 3.1866355454f, 3.5407061616f,
  3.9341179573f, 4.3712421748f, 4.8569357498f};

// ---------------- W pre-conversion: fp32 -> f16, frag-step layout, PRE-SWIZZLED ----
// Bs is filled linearly by global_load_lds, so the bank-conflict swizzle
// (chunk' = chunk ^ (row&3), 16B granularity) is applied HERE to the source.
__global__ __launch_bounds__(256) void convert_w(
    const float* __restrict__ W, _Float16* __restrict__ w16)
{
  int i = blockIdx.x * 256 + threadIdx.x;
  int c = i >> 10, k = i & 1023;
  int s = k >> 5, kk = k & 31;
  int kks = kk ^ ((c & 3) << 3);          // XOR f16-index bits 3-4 with row bits 0-1
  w16[s * (NPROJ * 32) + c * 32 + kks] = (_Float16)W[i];
}

// ---------------- MFMA projection GEMM: pure f16, fused k-normalize, swizzled LDS ----
constexpr int BM = 128, BK = 32, NS = D_DIM / BK;

__global__ __launch_bounds__(512, 2) void proj_gemm(
    const float* __restrict__ x, const _Float16* __restrict__ w16,
    _Float16* __restrict__ pf16)
{
  __shared__ __align__(16) _Float16 smem[2 * BM * BK + 2 * NPROJ * BK]; // 40 KB
  __shared__ float nrm[BM][2];

  _Float16 (*As)[BM * BK]    = (_Float16(*)[BM * BK])smem;
  _Float16 (*Bs)[NPROJ * BK] = (_Float16(*)[NPROJ * BK])(smem + 2 * BM * BK);
  _Float16 (*ep)[200]        = (_Float16(*)[200])smem;   // 64 x 200 f16 = 25.6 KB

  const int tid  = threadIdx.x;
  const int w    = tid >> 6, lane = tid & 63;
  const int wr   = w >> 2, wc = w & 3;      // wave grid 2x4
  const int fr   = lane & 15, fg = lane >> 4;
  const int row0 = blockIdx.x * BM;

  const int arow = tid >> 2, akq = (tid & 3) * 8;
  const int akqs = ((tid & 3) ^ (arow & 3)) * 8;   // swizzled LDS chunk for A write
  const int xa   = fr & 3;                          // read-side row&3 (rows offset by mult of 4)
  const float* aSrc = x + (size_t)(row0 + arow) * D_DIM + akq;

  f32x4 acc[4][3];
#pragma unroll
  for (int i = 0; i < 4; ++i)
#pragma unroll
    for (int j = 0; j < 3; ++j) acc[i][j] = (f32x4){0.f, 0.f, 0.f, 0.f};

  float4 a0, a1;

  auto loadA = [&](int s) {
    const float* p = aSrc + s * BK;
    a0 = *(const float4*)p;
    a1 = *(const float4*)(p + 4);
  };
  auto writeA = [&](int buf) {
    f16x8 h;
    h[0] = (_Float16)a0.x; h[1] = (_Float16)a0.y;
    h[2] = (_Float16)a0.z; h[3] = (_Float16)a0.w;
    h[4] = (_Float16)a1.x; h[5] = (_Float16)a1.y;
    h[6] = (_Float16)a1.z; h[7] = (_Float16)a1.w;
    *(f16x8*)&As[buf][arow * BK + akqs] = h;      // swizzled write
  };
  auto stageB = [&](int buf, int s) {
#pragma unroll
    for (int j = 0; j < 2; ++j) {
      const int sl = j * 8 + w;
      if (sl < 12) {
        const _Float16* src = w16 + (size_t)s * (NPROJ * 32) + sl * 512;
        __builtin_amdgcn_global_load_lds(
            (const __attribute__((address_space(1))) unsigned int*)(src) + lane * 4,
            (__attribute__((address_space(3))) unsigned int*)&Bs[buf][sl * 512],
            16, 0, 0);
      }
    }
  };
  auto compute = [&](int buf) {
    f16x8 af[4];
#pragma unroll
    for (int ar = 0; ar < 4; ++ar)
      af[ar] = *(const f16x8*)&As[buf][(wr * 64 + ar * 16 + fr) * BK + (fg ^ xa) * 8];
#pragma unroll
    for (int bc = 0; bc < 3; ++bc) {
      f16x8 bf = *(const f16x8*)&Bs[buf][(wc * 48 + bc * 16 + fr) * BK + (fg ^ xa) * 8];
#pragma unroll
      for (int ar = 0; ar < 4; ++ar)
        acc[ar][bc] = __builtin_amdgcn_mfma_f32_16x16x32_f16(af[ar], bf, acc[ar][bc], 0, 0, 0);
    }
  };

  loadA(0);
  stageB(0, 0);
  writeA(0);
  __syncthreads();

  int buf = 0;
  for (int s = 0; s < NS; ++s) {
    if (s + 1 < NS) {
      loadA(s + 1);
      stageB(buf ^ 1, s + 1);
    }
    compute(buf);
    if (s + 1 < NS) writeA(buf ^ 1);
    __syncthreads();
    buf ^= 1;
  }

  // ---- fused k-normalization (cols 0..63 are k) ----
  if (wc < 2) {
#pragma unroll
    for (int ar = 0; ar < 4; ++ar)
#pragma unroll
      for (int r = 0; r < 4; ++r) {
        float ss;
        if (wc == 0) {
          const float p0 = acc[ar][0][r], p1 = acc[ar][1][r], p2 = acc[ar][2][r];
          ss = p0 * p0 + p1 * p1 + p2 * p2;    // cols 0..47
        } else {
          const float p0 = acc[ar][0][r];
          ss = p0 * p0;                         // cols 48..63
        }
        ss += __shfl_xor(ss, 1, 64);
        ss += __shfl_xor(ss, 2, 64);
        ss += __shfl_xor(ss, 4, 64);
        ss += __shfl_xor(ss, 8, 64);
        if (fr == 0) nrm[wr * 64 + ar * 16 + fg * 4 + r][wc] = ss;
      }
  }
  __syncthreads();
  if (wc < 2) {
#pragma unroll
    for (int ar = 0; ar < 4; ++ar)
#pragma unroll
      for (int r = 0; r < 4; ++r) {
        const int row = wr * 64 + ar * 16 + fg * 4 + r;
        const float rn = 1.0f / (sqrtf(nrm[row][0] + nrm[row][1]) + EPS);
        if (wc == 0) {
          acc[ar][0][r] *= rn; acc[ar][1][r] *= rn; acc[ar][2][r] *= rn;
        } else {
          acc[ar][0][r] *= rn;
        }
      }
  }

  // ---- epilogue: LDS transpose -> coalesced f16x8 stores, two 64-row passes ----
#pragma unroll
  for (int p = 0; p < 2; ++p) {
    __syncthreads();
    if (wr == p) {
#pragma unroll
      for (int ar = 0; ar < 4; ++ar)
#pragma unroll
        for (int bc = 0; bc < 3; ++bc)
#pragma unroll
          for (int r = 0; r < 4; ++r)
            ep[ar * 16 + fg * 4 + r][wc * 48 + bc * 16 + fr] = (_Float16)acc[ar][bc][r];
    }
    __syncthreads();
#pragma unroll
    for (int u = 0; u < 3; ++u) {
      const int g = u * 512 + tid;        // f16x8 index in [0, 1536)
      const int rr = g / 24, cc = g - rr * 24;
      *(f16x8*)(pf16 + (size_t)(row0 + p * 64 + rr) * NPROJ + cc * 8) =
          *(const f16x8*)&ep[rr][cc * 8];
    }
  }
}

// ---------------- chunked scan (SW formulation), 1 wave, 37.1 KB LDS (R13, frozen) ----
__global__ __launch_bounds__(64) void scan_sw(
    const _Float16* __restrict__ pf16, const float* __restrict__ S0,
    float* __restrict__ out, float* __restrict__ Sfin)
{
  __shared__ __align__(16) _Float16 sK[64][72];     // 9216
  __shared__ __align__(16) _Float16 sQ[32][72];     // 4608 (Q half)
  __shared__ __align__(16) _Float16 sSW[64][72];    // 9216
  __shared__ __align__(16) _Float16 sDT[64][72];    // 9216 delta^T [i][tau]
  __shared__ __align__(16) _Float16 sBB[16][72];    // 2304 bridge+combine [t][i]
  __shared__ __align__(16) _Float16 uGt[2][16][40]; // 2560 gram tiles (dbuf)

  const int lane = threadIdx.x;
  const int fr = lane & 15, fg = lane >> 4;
  const int b = blockIdx.x & (B_DIM - 1), c = blockIdx.x >> 4;
  const int t0o = c * 64;
  const bool c0 = (c == 0);

  // zero sDT (bridge/H MFMAs read not-yet-written / padded columns: 0*NaN = NaN)
#pragma unroll
  for (int u = 0; u < 36; ++u) ((unsigned*)&sDT[0][0])[u * 64 + lane] = 0u;
  // zero uGt entirely (mm reads cols 16..31 expect 0)
#pragma unroll
  for (int u = 0; u < 10; ++u) ((unsigned*)&uGt[0][0][0])[u * 64 + lane] = 0u;

  auto stage64 = [&](_Float16 (*dst)[72], int t0, int sel) {
#pragma unroll
    for (int it = 0; it < 8; ++it) {
      int g = it * 64 + lane, t = g >> 3, c8 = g & 7;
      uint4 v = *(const uint4*)(pf16 + ((size_t)(t0 + t) * B_DIM + b) * NPROJ + sel + c8 * 8);
      *(uint4*)&dst[t][c8 * 8] = v;
    }
  };
  auto stageQ = [&](int half) {
#pragma unroll
    for (int it = 0; it < 4; ++it) {
      int g = it * 64 + lane, t = g >> 3, c8 = g & 7;
      uint4 v = *(const uint4*)(pf16 +
          ((size_t)(t0o + half * 32 + t) * B_DIM + b) * NPROJ + 128 + c8 * 8);
      *(uint4*)&sQ[t][c8 * 8] = v;
    }
  };

  auto dotT = [&](const _Float16* A, int sa, int ra, const _Float16* B, int sb, int rb) {
    f32x4 a = (f32x4){0.f, 0.f, 0.f, 0.f};
    f16x8 af = *(const f16x8*)(A + (ra + fr) * sa + fg * 8);
    f16x8 bf = *(const f16x8*)(B + (rb + fr) * sb + fg * 8);
    a = __builtin_amdgcn_mfma_f32_16x16x32_f16(af, bf, a, 0, 0, 0);
    af = *(const f16x8*)(A + (ra + fr) * sa + 32 + fg * 8);
    bf = *(const f16x8*)(B + (rb + fr) * sb + 32 + fg * 8);
    a = __builtin_amdgcn_mfma_f32_16x16x32_f16(af, bf, a, 0, 0, 0);
    return a;
  };

  // in-place K transpose: single wave; compiler barrier pins read-all-then-write order
  auto transposeK = [&]() {
    f16x8 rv[8];
#pragma unroll
    for (int q8 = 0; q8 < 8; ++q8) rv[q8] = *(const f16x8*)&sK[lane][q8 * 8];
    asm volatile("" ::: "memory");
#pragma unroll
    for (int q8 = 0; q8 < 8; ++q8)
#pragma unroll
      for (int e = 0; e < 8; ++e) sK[q8 * 8 + e][lane] = rv[q8][e];
  };

  // forward-substitution solve; diag Grams pre-hoisted to regs; combine folded into bacc
  auto solve = [&](bool isW, int t0v) {
    f32x4 gdA[4];
#pragma unroll
    for (int k = 0; k < 4; ++k)
      gdA[k] = dotT(&sK[0][0], 72, k * 16, &sK[0][0], 72, k * 16);

#pragma unroll
    for (int k = 0; k < 4; ++k) {
      _Float16 vr[16];
#pragma unroll
      for (int t = 0; t < 16; ++t)
        vr[t] = pf16[((size_t)(t0v + k * 16 + t) * B_DIM + b) * NPROJ + 64 + lane];

      f32x4 bacc[4];
#pragma unroll
      for (int ib = 0; ib < 4; ++ib) bacc[ib] = (f32x4){0.f, 0.f, 0.f, 0.f};

      if (k > 0) {
        for (int j = 0; j < k; ++j) {
          f32x4 g = dotT(&sK[0][0], 72, k * 16, &sK[0][0], 72, j * 16);
#pragma unroll
          for (int r = 0; r < 4; ++r) {
            const int tl = fg * 4 + r;
            const float e = isW ? (float)(16 * k + tl - 64)
                                : (float)(16 * (k - j) + tl - fr - 1);
            uGt[j & 1][tl][fr] = (_Float16)(g[r] * powA(e));
          }
#pragma unroll
          for (int ib = 0; ib < 4; ++ib) {
            f16x8 af = *(const f16x8*)&uGt[j & 1][fr][fg * 8];
            f16x8 bf = *(const f16x8*)&sDT[ib * 16 + fr][j * 16 + fg * 8];
            bacc[ib] = __builtin_amdgcn_mfma_f32_16x16x32_f16(af, bf, bacc[ib], 0, 0, 0);
          }
        }
      }

      if (!isW) {
#pragma unroll
        for (int tj = 0; tj < 4; ++tj) {
          f32x4 a = dotT(&sK[0][0], 72, k * 16, &sSW[0][0], 72, tj * 16);
#pragma unroll
          for (int r = 0; r < 4; ++r)
            bacc[tj][r] = fmaf(a[r], powA((float)(16 * k + fg * 4 + r)), bacc[tj][r]);
        }
      }

      const bool useBB = (!isW || k > 0);
      if (useBB) {
#pragma unroll
        for (int ib = 0; ib < 4; ++ib)
#pragma unroll
          for (int r = 0; r < 4; ++r)
            sBB[fg * 4 + r][ib * 16 + fr] = (_Float16)bacc[ib][r];
      }

      const f32x4 gd = gdA[k];

      float d[16], dA[16];
#pragma unroll
      for (int t = 0; t < 16; ++t) {
        float base = (float)vr[t];
        if (useBB) base -= (float)sBB[t][lane];
        float p0 = 0.f, p1 = 0.f, p2 = 0.f, p3 = 0.f;
#pragma unroll
        for (int tau = 0; tau < t; ++tau) {
          const float gv = rdlane(gd[t & 3], (t >> 2) * 16 + tau);
          if ((tau & 3) == 0)      p0 = fmaf(gv, dA[tau], p0);
          else if ((tau & 3) == 1) p1 = fmaf(gv, dA[tau], p1);
          else if ((tau & 3) == 2) p2 = fmaf(gv, dA[tau], p2);
          else                     p3 = fmaf(gv, dA[tau], p3);
        }
        const float sum = (p0 + p1) + (p2 + p3);
        d[t] = (t == 0) ? base : fmaf(-APOW[t - 1], sum, base);
        dA[t] = d[t] * AINV[t];
      }
#pragma unroll
      for (int t8 = 0; t8 < 2; ++t8) {
        f16x8 pack;
#pragma unroll
        for (int e = 0; e < 8; ++e) {
          const int tl = t8 * 8 + e;
          const float sc = isW ? powA((float)(63 - (16 * k + tl))) : 1.f;
          pack[e] = (_Float16)(d[tl] * sc);
        }
        *(f16x8*)&sDT[lane][k * 16 + t8 * 8] = pack;
      }
    }
  };

  // ---------------- phase W -> SW ----------------
  if (!c0) {
    stage64(sK, t0o - 64, 0);
    solve(true, t0o - 64);        // sDT = a^{63-tau} * delta_w
    transposeK();                 // sK := Kw^T (in place)
#pragma unroll
    for (int ti = 0; ti < 4; ++ti)
#pragma unroll
      for (int tj = 0; tj < 4; ++tj) {
        f32x4 a = dotT(&sDT[0][0], 72, ti * 16, &sK[0][0], 72, tj * 16);
#pragma unroll
        for (int r = 0; r < 4; ++r)
          sSW[ti * 16 + fg * 4 + r][tj * 16 + fr] = (_Float16)a[r];
      }
  } else {
#pragma unroll
    for (int it = 0; it < 8; ++it) {
      const int row = it * 8 + (lane >> 3), col = (lane & 7) * 8;
      const float* src = S0 + (size_t)b * 4096 + row * 64 + col;
      const float4 v1 = *(const float4*)src;
      const float4 v2 = *(const float4*)(src + 4);
      f16x8 pk;
      pk[0] = (_Float16)v1.x; pk[1] = (_Float16)v1.y;
      pk[2] = (_Float16)v1.z; pk[3] = (_Float16)v1.w;
      pk[4] = (_Float16)v2.x; pk[5] = (_Float16)v2.y;
      pk[6] = (_Float16)v2.z; pk[7] = (_Float16)v2.w;
      *(f16x8*)&sSW[row][col] = pk;
    }
  }

  // ---------------- phase O ----------------
  stage64(sK, t0o, 0);            // Ko
  stageQ(0);                      // Q rows 0..31 (latency hides under solve)
  solve(false, t0o);              // sDT = delta_o

#pragma unroll
  for (int h2 = 0; h2 < 2; ++h2) {
    if (h2) stageQ(1);
#pragma unroll
    for (int tb2 = 0; tb2 < 2; ++tb2) {
      const int tb = h2 * 2 + tb2;
      f32x4 sq[4];
#pragma unroll
      for (int tj = 0; tj < 4; ++tj) {
        f32x4 a = dotT(&sQ[0][0], 72, tb2 * 16, &sSW[0][0], 72, tj * 16);
#pragma unroll
        for (int r = 0; r < 4; ++r)
          a[r] *= powA((float)(tb * 16 + fg * 4 + r + 1));
        sq[tj] = a;
      }
      for (int qb = 0; qb <= tb; ++qb) {
        f32x4 h = dotT(&sQ[0][0], 72, tb2 * 16, &sK[0][0], 72, qb * 16);
#pragma unroll
        for (int r = 0; r < 4; ++r) {
          const int tl = fg * 4 + r;
          const int t = tb * 16 + tl, tau = qb * 16 + fr;
          const float val = (tau <= t) ? h[r] * powA((float)(t - tau)) : 0.f;
          uGt[qb & 1][tl][fr] = (_Float16)val;
        }
#pragma unroll
        for (int ib = 0; ib < 4; ++ib) {
          f16x8 af = *(const f16x8*)&uGt[qb & 1][fr][fg * 8];
          f16x8 bf = *(const f16x8*)&sDT[ib * 16 + fr][qb * 16 + fg * 8];
          sq[ib] = __builtin_amdgcn_mfma_f32_16x16x32_f16(af, bf, sq[ib], 0, 0, 0);
        }
      }
#pragma unroll
      for (int tj = 0; tj < 4; ++tj)
#pragma unroll
        for (int r = 0; r < 4; ++r) {
          const int t = tb * 16 + fg * 4 + r, i = tj * 16 + fr;
          const float Sq = sq[tj][r];
          const float sig = 1.0f / (1.0f + __expf(-Sq));
          out[(size_t)(t0o + t) * 1024 + b * 64 + i] = Sq * Sq * sig;
        }
    }
  }

  // ---------------- final state (c == 63) ----------------
  if (c == NCHUNK - 1) {
#pragma unroll
    for (int t8 = 0; t8 < 8; ++t8) {
      f16x8 v = *(const f16x8*)&sDT[lane][t8 * 8];
#pragma unroll
      for (int e = 0; e < 8; ++e)
        v[e] = (_Float16)((float)v[e] * powA((float)(63 - (t8 * 8 + e))));
      *(f16x8*)&sDT[lane][t8 * 8] = v;
    }
    transposeK();   // sK := Ko^T (in place)
#pragma unroll
    for (int ti = 0; ti < 4; ++ti)
#pragma unroll
      for (int tj = 0; tj < 4; ++tj) {
        f32x4 so = dotT(&sDT[0][0], 72, ti * 16, &sK[0][0], 72, tj * 16);
#pragma unroll
        for (int r = 0; r < 4; ++r) {
          const int i = ti * 16 + fg * 4 + r, j = tj * 16 + fr;
          Sfin[((size_t)b * 64 + i) * 64 + j] = A64F * (float)sSW[i][j] + so[r];
        }
      }
  }
}

extern "C" void kernel_launch(void* const* d_in, const int* in_sizes, int n_in,
                              void* d_out, int out_size, void* d_ws, size_t ws_size,
                              hipStream_t stream)
{
  const float* x  = (const float*)d_in[0];
  const float* S0 = (const float*)d_in[1];
  const float* Wk = (const float*)d_in[2];
  float* out  = (float*)d_out;
  float* Sfin = out + (size_t)T_DIM * B_DIM * N_DIM;

  // ws layout: pf16 (25.17 MB) | w16 (384 KB)
  char* wsb = (char*)d_ws;
  _Float16* pf16 = (_Float16*)(wsb);
  _Float16* w16  = (_Float16*)(wsb + 25165824);

  convert_w<<<(NPROJ * D_DIM) / 256, 256, 0, stream>>>(Wk, w16);
  proj_gemm<<<(T_DIM * B_DIM) / BM, 512, 0, stream>>>(x, w16, pf16);
  scan_sw<<<B_DIM * NCHUNK, 64, 0, stream>>>(pf16, S0, out, Sfin);
}